// Round 3
// baseline (166.905 us; speedup 1.0000x reference)
//
#include <hip/hip_runtime.h>
#include <hip/hip_bf16.h>
#include <math.h>

#define EPSV 1e-6f
#define LAMBDAV 1e-3f
#define LN_2PI 1.8378770664093453f

__device__ __forceinline__ float bflo(unsigned int u) {
    union { unsigned int i; float f; } x; x.i = u << 16; return x.f;
}
__device__ __forceinline__ float bfhi(unsigned int u) {
    union { unsigned int i; float f; } x; x.i = u & 0xffff0000u; return x.f;
}
__device__ __forceinline__ unsigned short f2bf(float f) {
    __hip_bfloat16 h = __float2bfloat16(f);
    return *(unsigned short*)&h;
}

typedef __attribute__((ext_vector_type(8))) short s8v;
typedef __attribute__((ext_vector_type(4))) float f4v;
typedef __attribute__((ext_vector_type(2))) int i2v;

// DPP lane-permute move (VALU-latency cross-lane, no LDS pipe).
template<int CTRL>
__device__ __forceinline__ float dpp_mv(float x) {
    return __int_as_float(__builtin_amdgcn_update_dpp(
        0, __float_as_int(x), CTRL, 0xF, 0xF, true));
}
__device__ __forceinline__ float x16_sum(float x) {
#if __has_builtin(__builtin_amdgcn_permlane16_swap)
    i2v r = __builtin_amdgcn_permlane16_swap(__float_as_int(x), __float_as_int(x), false, false);
    return __int_as_float(r.x) + __int_as_float(r.y);
#else
    return x + __int_as_float(__builtin_amdgcn_ds_swizzle(__float_as_int(x), 0x401F));
#endif
}
__device__ __forceinline__ float x16_max(float x) {
#if __has_builtin(__builtin_amdgcn_permlane16_swap)
    i2v r = __builtin_amdgcn_permlane16_swap(__float_as_int(x), __float_as_int(x), false, false);
    return fmaxf(__int_as_float(r.x), __int_as_float(r.y));
#else
    return fmaxf(x, __int_as_float(__builtin_amdgcn_ds_swizzle(__float_as_int(x), 0x401F)));
#endif
}
__device__ __forceinline__ float xhalf_sum(float x) {
#if __has_builtin(__builtin_amdgcn_permlane32_swap)
    i2v r = __builtin_amdgcn_permlane32_swap(__float_as_int(x), __float_as_int(x), false, false);
    return __int_as_float(r.x) + __int_as_float(r.y);
#else
    return x + __shfl_xor(x, 32, 64);
#endif
}
__device__ __forceinline__ float red_max32(float x) {
    x = fmaxf(x, dpp_mv<0xB1>(x));    // quad_perm [1,0,3,2]  (xor 1)
    x = fmaxf(x, dpp_mv<0x4E>(x));    // quad_perm [2,3,0,1]  (xor 2)
    x = fmaxf(x, dpp_mv<0x124>(x));   // row_ror:4
    x = fmaxf(x, dpp_mv<0x128>(x));   // row_ror:8
    return x16_max(x);
}
__device__ __forceinline__ float red_sum32(float x) {
    x += dpp_mv<0xB1>(x);
    x += dpp_mv<0x4E>(x);
    x += dpp_mv<0x124>(x);
    x += dpp_mv<0x128>(x);
    return x16_sum(x);
}
__device__ __forceinline__ float red_sum16(float x) {
    x += dpp_mv<0xB1>(x);
    x += dpp_mv<0x4E>(x);
    x += dpp_mv<0x124>(x);
    x += dpp_mv<0x128>(x);
    return x;
}

// Device-coherent (AGENT scope) scalar access for cross-block exchange.
__device__ __forceinline__ void g_store(float* p, float v) {
    __hip_atomic_store(p, v, __ATOMIC_RELAXED, __HIP_MEMORY_SCOPE_AGENT);
}
__device__ __forceinline__ float g_load(const float* p) {
    return __hip_atomic_load(p, __ATOMIC_RELAXED, __HIP_MEMORY_SCOPE_AGENT);
}

// Kernel 1: MFMA conv, M-split: 576 blocks = (i2, cq-half). 30KB LDS/block ->
// ~5 blocks/CU capacity, removes the 288=256+32 two-round quantization.
__global__ __launch_bounds__(256)
void conv_v_kernel(const float* __restrict__ x, const float* __restrict__ w,
                   __hip_bfloat16* __restrict__ vout, unsigned int* __restrict__ flags)
{
    __shared__ unsigned short wb[256 * 40];  // [cq_local][p pad40]
    __shared__ unsigned short pb[128 * 40];  // [n][p pad40]

    const int bid = blockIdx.x;
    const int i2  = bid >> 1;
    const int mh  = bid & 1;                 // cq half: [mh*256, mh*256+256)
    const int tid = threadIdx.x;

    if (bid == 0) {                          // zero em's pairwise-barrier flags
        for (int u = tid; u < 384; u += 256) flags[u] = 0;
    }

    // zero k=16..31 padding (mfma reads k<32)
    for (int u = tid; u < 256 * 8; u += 256) {
        int r = u >> 3, j = u & 7;
        *(unsigned int*)&wb[r * 40 + 16 + j * 2] = 0;
    }
    for (int u = tid; u < 128 * 8; u += 256) {
        int r = u >> 3, j = u & 7;
        *(unsigned int*)&pb[r * 40 + 16 + j * 2] = 0;
    }
    // stage w[i2][c][p][q] fp32 -> wb[(c_local*16+q)][p] bf16 for c_local 0..15
    #pragma unroll 4
    for (int u = 0; u < 16; ++u) {
        int idx = u * 256 + tid;               // cl*256 + p*16 + q
        int cl = idx >> 8, p = (idx >> 4) & 15, q = idx & 15;
        wb[(cl * 16 + q) * 40 + p] = f2bf(w[(size_t)i2 * 8192 + mh * 4096 + idx]);
    }
    // fused gather: pb[nn][p] from x via reference reshape scramble
    #pragma unroll
    for (int u = 0; u < 8; ++u) {
        int idx = u * 256 + tid;               // nn*16 + p
        int nn = idx >> 4, p = idx & 15;
        int e  = i2 * 16 + p;
        int k2 = e >> 9, c2 = e & 511;
        int f  = k2 * 544 + c2;
        int ci = f / 9, kk = f - ci * 9;
        int bi = nn >> 6, oi = (nn >> 3) & 7, oj = nn & 7;
        int row = 2 * oi + kk / 3 - 1;
        int col = 2 * oj + (kk - (kk / 3) * 3) - 1;
        float val = 0.f;
        if ((unsigned)row < 16u && (unsigned)col < 16u)
            val = x[((bi * 16 + row) * 16 + col) * 544 + ci];
        pb[nn * 40 + p] = f2bf(val);
    }
    __syncthreads();

    const int lane = tid & 63;
    const int wv   = tid >> 6;
    const int l16  = lane & 15;
    const int quad = lane >> 4;
    const int cq0l = wv * 64;                  // local cq base of this wave

    s8v afrag[4], bfrag[8];
    #pragma unroll
    for (int mt = 0; mt < 4; ++mt)
        afrag[mt] = *(const s8v*)&wb[(cq0l + mt * 16 + l16) * 40 + quad * 8];
    #pragma unroll
    for (int nt = 0; nt < 8; ++nt)
        bfrag[nt] = *(const s8v*)&pb[(nt * 16 + l16) * 40 + quad * 8];

    #pragma unroll
    for (int nt = 0; nt < 8; ++nt) {
        const int nl = nt * 16 + l16;
        #pragma unroll
        for (int mt = 0; mt < 4; ++mt) {
            f4v acc = {0.f, 0.f, 0.f, 0.f};
            acc = __builtin_amdgcn_mfma_f32_16x16x32_bf16(afrag[mt], bfrag[nt], acc, 0, 0, 0);
            int cq = mh * 256 + cq0l + mt * 16 + quad * 4;
            unsigned int lo = f2bf(acc[0]) | ((unsigned int)f2bf(acc[1]) << 16);
            unsigned int hi = f2bf(acc[2]) | ((unsigned int)f2bf(acc[3]) << 16);
            uint2 pk; pk.x = lo; pk.y = hi;
            *(uint2*)((unsigned short*)vout + ((size_t)nl * 288 + i2) * 512 + cq) = pk;
        }
    }
}

// Kernel 2: EM routing, grid 256 = (n, row-half h). Each block: 16 waves, wave
// wv owns rows {k*16+wv : k in [9h, 9h+9)} = 4 pairs + 1 tail. Per-(c,q)
// partials are exchanged with the partner block (bid ^ 128 -> same XCD slot)
// via AGENT-scope global stores/loads + release/acquire flag barrier.
__global__ __launch_bounds__(1024, 4)
void em_routing_kernel(const float* __restrict__ x,
                       const unsigned short* __restrict__ v,   // [n][i][cq] bf16
                       const float* __restrict__ beta_u,
                       const float* __restrict__ beta_a,
                       float* __restrict__ part,               // [t][n][h][1088]
                       unsigned int* __restrict__ flags,       // [t][n]
                       float* __restrict__ out)
{
    __shared__ float fct_s[288];            // a/(a+eps)
    __shared__ float red_s[16 * 64 * 17];   // [wave][lane][s0|s1[8]|s2[8]]
    __shared__ float mu_s[32 * 17];
    __shared__ float i2ss_s[32 * 17];
    __shared__ float aout_s[32];
    __shared__ float kc_s[32];
    __shared__ float pad_s[1600];           // force 1 block/CU (LDS > 80KB)

    const int bid = blockIdx.x;
    const int n   = bid & 127;
    const int h   = bid >> 7;               // row half: k in [9h, 9h+9)
    const int tid = threadIdx.x;
    const int bi = n >> 6, oi = (n >> 3) & 7, oj = n & 7;
    if (tid == 1023) pad_s[0] = 0.f;        // keep pad_s allocated

    if (tid < 288) {
        int k2 = tid >> 5;
        int c2 = 512 + (tid & 31);
        int f  = k2 * 544 + c2;
        int ci = f / 9;
        int kk = f - ci * 9;
        int row = 2 * oi + kk / 3 - 1;
        int col = 2 * oj + (kk - (kk / 3) * 3) - 1;
        float a = 0.f;
        if ((unsigned)row < 16u && (unsigned)col < 16u)
            a = x[((bi * 16 + row) * 16 + col) * 544 + ci];
        fct_s[tid] = a / (a + EPSV);   // sum_c r*a == a -> rr = softmax * fct
    }
    __syncthreads();

    const unsigned short* vb = v + (size_t)n * 288 * 512;
    const int wv   = tid >> 6;      // wave 0..15
    const int lane = tid & 63;
    const int c    = lane & 31;
    const int qh   = lane >> 5;     // q-half 0/1
    const int qb   = qh * 8;
    const int kbase = 9 * h;
    const unsigned short* base = vb + c * 16 + qb;

    for (int t = 0; t < 3; ++t) {
        float mu8[8], is8[8], kcv = 0.f;
        if (t > 0) {
            #pragma unroll
            for (int j = 0; j < 8; ++j) {
                mu8[j] = mu_s[c * 17 + qb + j];
                is8[j] = i2ss_s[c * 17 + qb + j];
            }
            kcv = kc_s[c];
        }

        float s0 = 0.f, s1[8], s2[8];
        #pragma unroll
        for (int j = 0; j < 8; ++j) { s1[j] = 0.f; s2[j] = 0.f; }

        // prefetch pair 0
        uint4 ua = *(const uint4*)(base + (size_t)((kbase + 0) * 16 + wv) * 512);
        uint4 ub = *(const uint4*)(base + (size_t)((kbase + 1) * 16 + wv) * 512);

        for (int kp = 0; kp < 4; ++kp) {
            const int ia = (kbase + 2 * kp) * 16 + wv;
            const int ib = ia + 16;
            uint4 una, unb;
            if (kp < 3) {
                una = *(const uint4*)(base + (size_t)(ia + 32) * 512);
                unb = *(const uint4*)(base + (size_t)(ia + 48) * 512);
            } else {
                una = *(const uint4*)(base + (size_t)((kbase + 8) * 16 + wv) * 512);
                unb = una;
            }
            float va[8], vvb[8];
            va[0] = bflo(ua.x); va[1] = bfhi(ua.x);
            va[2] = bflo(ua.y); va[3] = bfhi(ua.y);
            va[4] = bflo(ua.z); va[5] = bfhi(ua.z);
            va[6] = bflo(ua.w); va[7] = bfhi(ua.w);
            vvb[0] = bflo(ub.x); vvb[1] = bfhi(ub.x);
            vvb[2] = bflo(ub.y); vvb[3] = bfhi(ub.y);
            vvb[4] = bflo(ub.z); vvb[5] = bfhi(ub.z);
            vvb[6] = bflo(ub.w); vvb[7] = bfhi(ub.w);

            float rra, rrb;
            if (t == 0) {
                rra = fct_s[ia] * 0.03125f;
                rrb = fct_s[ib] * 0.03125f;
            } else {
                float pa = 0.f, pb2 = 0.f;
                #pragma unroll
                for (int j = 0; j < 8; ++j) {
                    float da = va[j] - mu8[j];
                    float db = vvb[j] - mu8[j];
                    pa  += da * da * is8[j];
                    pb2 += db * db * is8[j];
                }
                pa  = xhalf_sum(pa);      // combine q-halves (xor32, VALU)
                pb2 = xhalf_sum(pb2);
                float acca = kcv - pa;
                float accb = kcv - pb2;
                float mxa = red_max32(acca);
                float mxb = red_max32(accb);
                float ea = __expf(acca - mxa);
                float eb = __expf(accb - mxb);
                float sa = red_sum32(ea);
                float sb = red_sum32(eb);
                rra = (ea / sa) * fct_s[ia];
                rrb = (eb / sb) * fct_s[ib];
            }

            s0 += rra + rrb;
            #pragma unroll
            for (int j = 0; j < 8; ++j) {
                s1[j] += rra * va[j] + rrb * vvb[j];
                s2[j] += rra * va[j] * va[j] + rrb * vvb[j] * vvb[j];
            }
            ua = una; ub = unb;
        }
        // tail single row (k = kbase+8)
        {
            const int ia = (kbase + 8) * 16 + wv;
            float va[8];
            va[0] = bflo(ua.x); va[1] = bfhi(ua.x);
            va[2] = bflo(ua.y); va[3] = bfhi(ua.y);
            va[4] = bflo(ua.z); va[5] = bfhi(ua.z);
            va[6] = bflo(ua.w); va[7] = bfhi(ua.w);
            float rra;
            if (t == 0) {
                rra = fct_s[ia] * 0.03125f;
            } else {
                float pa = 0.f;
                #pragma unroll
                for (int j = 0; j < 8; ++j) {
                    float da = va[j] - mu8[j];
                    pa += da * da * is8[j];
                }
                pa = xhalf_sum(pa);
                float acca = kcv - pa;
                float mxa = red_max32(acca);
                float ea = __expf(acca - mxa);
                float sa = red_sum32(ea);
                rra = (ea / sa) * fct_s[ia];
            }
            s0 += rra;
            #pragma unroll
            for (int j = 0; j < 8; ++j) {
                s1[j] += rra * va[j];
                s2[j] += rra * va[j] * va[j];
            }
        }

        // per-wave partials -> LDS
        {
            float* dst = &red_s[(wv * 64 + lane) * 17];
            dst[0] = s0;
            #pragma unroll
            for (int j = 0; j < 8; ++j) { dst[1 + j] = s1[j]; dst[9 + j] = s2[j]; }
        }
        __syncthreads();

        float* gp_own        = part + (((size_t)t * 128 + n) * 2 + h) * 1088;
        const float* gp_peer = part + (((size_t)t * 128 + n) * 2 + (1 - h)) * 1088;
        unsigned int* flg    = flags + t * 128 + n;

        float S0 = 0.f, S1 = 0.f, S2 = 0.f;
        if (tid < 512) {
            const int c2 = tid >> 4, q2 = tid & 15;
            const int qh2 = q2 >> 3, j2 = q2 & 7;
            #pragma unroll
            for (int wvi = 0; wvi < 16; ++wvi) {
                S0 += red_s[(wvi * 64 + c2) * 17];
                const float* sp = &red_s[(wvi * 64 + qh2 * 32 + c2) * 17];
                S1 += sp[1 + j2];
                S2 += sp[9 + j2];
            }
            // publish this block's partials (device-coherent)
            g_store(gp_own + tid, S1);
            g_store(gp_own + 512 + tid, S2);
            if (q2 == 0) g_store(gp_own + 1024 + c2, S0);
        }
        __syncthreads();   // all stores drained (vmcnt) before flag
        if (tid == 0) {
            __hip_atomic_fetch_add(flg, 1u, __ATOMIC_RELEASE, __HIP_MEMORY_SCOPE_AGENT);
            int guard = 0;
            while (__hip_atomic_load(flg, __ATOMIC_ACQUIRE, __HIP_MEMORY_SCOPE_AGENT) < 2u
                   && guard < (1 << 22)) { __builtin_amdgcn_s_sleep(2); ++guard; }
        }
        __syncthreads();

        if (tid < 512) {
            const int c2 = tid >> 4, q2 = tid & 15;
            S1 += g_load(gp_peer + tid);
            S2 += g_load(gp_peer + 512 + tid);
            S0 += g_load(gp_peer + 1024 + c2);
            float invr = 1.0f / (S0 + EPSV);
            float w0  = S0 * invr;
            float m   = S1 * invr;
            float s2p = S2 * invr;
            float sig = s2p - m * m * (2.0f - w0);   // == sum coeff*(v-mu)^2
            sig = fmaxf(sig + EPSV, 1e-4f);
            float hl = 0.5f * logf(sig);
            mu_s[c2 * 17 + q2]   = m;
            i2ss_s[c2 * 17 + q2] = 1.0f / (2.0f * sig);
            float shl = red_sum16(hl);
            if (q2 == 0) {
                float bu  = beta_u[c2];
                float cs  = (16.0f * bu + shl) * S0;
                float arg = LAMBDAV * (beta_a[c2] - cs);
                float ao  = 1.0f / (1.0f + expf(-arg));
                ao = fminf(fmaxf(ao, 1e-4f), 1.0f - 1e-4f);
                aout_s[c2] = ao;
                kc_s[c2]   = logf(ao + EPSV) - shl - 8.0f * LN_2PI;
            }
        }
        __syncthreads();
    }

    // epilogue (fp32), h==0 only: p_out | a_out | out
    if (h == 0 && tid < 512) {
        int c2 = tid >> 4, q2 = tid & 15;
        float mu = mu_s[c2 * 17 + q2];
        if (isnan(mu)) mu = 0.f;
        mu = fminf(fmaxf(mu, -10000.f), 10000.f);
        out[(size_t)n * 512 + tid] = mu;
        out[69632 + (size_t)n * 544 + tid] = mu;
        if (tid < 32) {
            float ao = aout_s[tid];
            if (isnan(ao)) ao = 0.5f;
            out[65536 + n * 32 + tid] = ao;
            out[69632 + n * 544 + 512 + tid] = ao;
        }
    }
}

extern "C" void kernel_launch(void* const* d_in, const int* in_sizes, int n_in,
                              void* d_out, int out_size, void* d_ws, size_t ws_size,
                              hipStream_t stream) {
    const float* x  = (const float*)d_in[0];
    const float* w  = (const float*)d_in[1];
    const float* bu = (const float*)d_in[2];
    const float* ba = (const float*)d_in[3];
    float* out = (float*)d_out;
    __hip_bfloat16* v = (__hip_bfloat16*)d_ws;               // 37.7 MB
    float* part        = (float*)((char*)d_ws + (38u << 20)); // 3.3 MB partials
    unsigned int* flags = (unsigned int*)((char*)d_ws + (43u << 20)); // 384 ints

    conv_v_kernel<<<dim3(576), dim3(256), 0, stream>>>(x, w, v, flags);
    em_routing_kernel<<<dim3(256), dim3(1024), 0, stream>>>(
        x, (const unsigned short*)v, bu, ba, part, flags, out);
}

// Round 4
// 122.324 us; speedup vs baseline: 1.3644x; 1.3644x over previous
//
#include <hip/hip_runtime.h>
#include <hip/hip_bf16.h>
#include <math.h>

#define EPSV 1e-6f
#define LAMBDAV 1e-3f
#define LN_2PI 1.8378770664093453f

__device__ __forceinline__ float bflo(unsigned int u) {
    union { unsigned int i; float f; } x; x.i = u << 16; return x.f;
}
__device__ __forceinline__ float bfhi(unsigned int u) {
    union { unsigned int i; float f; } x; x.i = u & 0xffff0000u; return x.f;
}
__device__ __forceinline__ unsigned short f2bf(float f) {
    __hip_bfloat16 h = __float2bfloat16(f);
    return *(unsigned short*)&h;
}

typedef __attribute__((ext_vector_type(8))) short s8v;
typedef __attribute__((ext_vector_type(4))) float f4v;
typedef __attribute__((ext_vector_type(2))) int i2v;

// DPP lane-permute move (VALU-latency cross-lane, no LDS pipe).
template<int CTRL>
__device__ __forceinline__ float dpp_mv(float x) {
    return __int_as_float(__builtin_amdgcn_update_dpp(
        0, __float_as_int(x), CTRL, 0xF, 0xF, true));
}
__device__ __forceinline__ float x16_sum(float x) {
#if __has_builtin(__builtin_amdgcn_permlane16_swap)
    i2v r = __builtin_amdgcn_permlane16_swap(__float_as_int(x), __float_as_int(x), false, false);
    return __int_as_float(r.x) + __int_as_float(r.y);
#else
    return x + __int_as_float(__builtin_amdgcn_ds_swizzle(__float_as_int(x), 0x401F));
#endif
}
__device__ __forceinline__ float x16_max(float x) {
#if __has_builtin(__builtin_amdgcn_permlane16_swap)
    i2v r = __builtin_amdgcn_permlane16_swap(__float_as_int(x), __float_as_int(x), false, false);
    return fmaxf(__int_as_float(r.x), __int_as_float(r.y));
#else
    return fmaxf(x, __int_as_float(__builtin_amdgcn_ds_swizzle(__float_as_int(x), 0x401F)));
#endif
}
__device__ __forceinline__ float xhalf_sum(float x) {
#if __has_builtin(__builtin_amdgcn_permlane32_swap)
    i2v r = __builtin_amdgcn_permlane32_swap(__float_as_int(x), __float_as_int(x), false, false);
    return __int_as_float(r.x) + __int_as_float(r.y);
#else
    return x + __shfl_xor(x, 32, 64);
#endif
}
__device__ __forceinline__ float red_max32(float x) {
    x = fmaxf(x, dpp_mv<0xB1>(x));    // quad_perm [1,0,3,2]  (xor 1)
    x = fmaxf(x, dpp_mv<0x4E>(x));    // quad_perm [2,3,0,1]  (xor 2)
    x = fmaxf(x, dpp_mv<0x124>(x));   // row_ror:4
    x = fmaxf(x, dpp_mv<0x128>(x));   // row_ror:8
    return x16_max(x);
}
__device__ __forceinline__ float red_sum32(float x) {
    x += dpp_mv<0xB1>(x);
    x += dpp_mv<0x4E>(x);
    x += dpp_mv<0x124>(x);
    x += dpp_mv<0x128>(x);
    return x16_sum(x);
}
__device__ __forceinline__ float red_sum16(float x) {
    x += dpp_mv<0xB1>(x);
    x += dpp_mv<0x4E>(x);
    x += dpp_mv<0x124>(x);
    x += dpp_mv<0x128>(x);
    return x;
}

// Kernel 1: MFMA conv, M-split: 576 blocks = (i2, cq-half). 30KB LDS/block ->
// ~5 blocks/CU capacity, removes the 288=256+32 two-round quantization.
__global__ __launch_bounds__(256)
void conv_v_kernel(const float* __restrict__ x, const float* __restrict__ w,
                   __hip_bfloat16* __restrict__ vout)
{
    __shared__ unsigned short wb[256 * 40];  // [cq_local][p pad40]
    __shared__ unsigned short pb[128 * 40];  // [n][p pad40]

    const int bid = blockIdx.x;
    const int i2  = bid >> 1;
    const int mh  = bid & 1;                 // cq half: [mh*256, mh*256+256)
    const int tid = threadIdx.x;

    // zero k=16..31 padding (mfma reads k<32)
    for (int u = tid; u < 256 * 8; u += 256) {
        int r = u >> 3, j = u & 7;
        *(unsigned int*)&wb[r * 40 + 16 + j * 2] = 0;
    }
    for (int u = tid; u < 128 * 8; u += 256) {
        int r = u >> 3, j = u & 7;
        *(unsigned int*)&pb[r * 40 + 16 + j * 2] = 0;
    }
    // stage w[i2][c][p][q] fp32 -> wb[(c_local*16+q)][p] bf16 for c_local 0..15
    #pragma unroll 4
    for (int u = 0; u < 16; ++u) {
        int idx = u * 256 + tid;               // cl*256 + p*16 + q
        int cl = idx >> 8, p = (idx >> 4) & 15, q = idx & 15;
        wb[(cl * 16 + q) * 40 + p] = f2bf(w[(size_t)i2 * 8192 + mh * 4096 + idx]);
    }
    // fused gather: pb[nn][p] from x via reference reshape scramble
    #pragma unroll
    for (int u = 0; u < 8; ++u) {
        int idx = u * 256 + tid;               // nn*16 + p
        int nn = idx >> 4, p = idx & 15;
        int e  = i2 * 16 + p;
        int k2 = e >> 9, c2 = e & 511;
        int f  = k2 * 544 + c2;
        int ci = f / 9, kk = f - ci * 9;
        int bi = nn >> 6, oi = (nn >> 3) & 7, oj = nn & 7;
        int row = 2 * oi + kk / 3 - 1;
        int col = 2 * oj + (kk - (kk / 3) * 3) - 1;
        float val = 0.f;
        if ((unsigned)row < 16u && (unsigned)col < 16u)
            val = x[((bi * 16 + row) * 16 + col) * 544 + ci];
        pb[nn * 40 + p] = f2bf(val);
    }
    __syncthreads();

    const int lane = tid & 63;
    const int wv   = tid >> 6;
    const int l16  = lane & 15;
    const int quad = lane >> 4;
    const int cq0l = wv * 64;                  // local cq base of this wave

    s8v afrag[4], bfrag[8];
    #pragma unroll
    for (int mt = 0; mt < 4; ++mt)
        afrag[mt] = *(const s8v*)&wb[(cq0l + mt * 16 + l16) * 40 + quad * 8];
    #pragma unroll
    for (int nt = 0; nt < 8; ++nt)
        bfrag[nt] = *(const s8v*)&pb[(nt * 16 + l16) * 40 + quad * 8];

    #pragma unroll
    for (int nt = 0; nt < 8; ++nt) {
        const int nl = nt * 16 + l16;
        #pragma unroll
        for (int mt = 0; mt < 4; ++mt) {
            f4v acc = {0.f, 0.f, 0.f, 0.f};
            acc = __builtin_amdgcn_mfma_f32_16x16x32_bf16(afrag[mt], bfrag[nt], acc, 0, 0, 0);
            int cq = mh * 256 + cq0l + mt * 16 + quad * 4;
            unsigned int lo = f2bf(acc[0]) | ((unsigned int)f2bf(acc[1]) << 16);
            unsigned int hi = f2bf(acc[2]) | ((unsigned int)f2bf(acc[3]) << 16);
            uint2 pk; pk.x = lo; pk.y = hi;
            *(uint2*)((unsigned short*)vout + ((size_t)nl * 288 + i2) * 512 + cq) = pk;
        }
    }
}

// Kernel 2: EM routing (R2 structure — best verified: ~41 us). One block per n,
// 16 waves; lane = (qh,c), 8 q x 2 rows per iteration; softmax cross-lane on
// the VALU pipe (DPP + permlane), phase-3 fused into phase-2 via DPP row-sum.
__global__ __launch_bounds__(1024, 4)
void em_routing_kernel(const float* __restrict__ x,
                       const unsigned short* __restrict__ v,   // [n][i][cq] bf16
                       const float* __restrict__ beta_u,
                       const float* __restrict__ beta_a,
                       float* __restrict__ out)
{
    __shared__ float fct_s[288];            // a/(a+eps)
    __shared__ float red_s[16 * 64 * 17];   // [wave][lane][s0|s1[8]|s2[8]]
    __shared__ float mu_s[32 * 17];
    __shared__ float i2ss_s[32 * 17];
    __shared__ float aout_s[32];
    __shared__ float kc_s[32];

    const int n   = blockIdx.x;
    const int tid = threadIdx.x;
    const int bi = n >> 6, oi = (n >> 3) & 7, oj = n & 7;

    if (tid < 288) {
        int k2 = tid >> 5;
        int c2 = 512 + (tid & 31);
        int f  = k2 * 544 + c2;
        int ci = f / 9;
        int kk = f - ci * 9;
        int row = 2 * oi + kk / 3 - 1;
        int col = 2 * oj + (kk - (kk / 3) * 3) - 1;
        float a = 0.f;
        if ((unsigned)row < 16u && (unsigned)col < 16u)
            a = x[((bi * 16 + row) * 16 + col) * 544 + ci];
        fct_s[tid] = a / (a + EPSV);   // sum_c r*a == a -> rr = softmax * fct
    }
    __syncthreads();

    const unsigned short* vb = v + (size_t)n * 288 * 512;
    const int wv   = tid >> 6;      // wave 0..15
    const int lane = tid & 63;
    const int c    = lane & 31;
    const int qh   = lane >> 5;     // q-half 0/1
    const int qb   = qh * 8;
    const unsigned short* base = vb + c * 16 + qb;

    for (int t = 0; t < 3; ++t) {
        float mu8[8], is8[8], kcv = 0.f;
        if (t > 0) {
            #pragma unroll
            for (int j = 0; j < 8; ++j) {
                mu8[j] = mu_s[c * 17 + qb + j];
                is8[j] = i2ss_s[c * 17 + qb + j];
            }
            kcv = kc_s[c];
        }

        float s0 = 0.f, s1[8], s2[8];
        #pragma unroll
        for (int j = 0; j < 8; ++j) { s1[j] = 0.f; s2[j] = 0.f; }

        // prefetch pair 0
        uint4 ua = *(const uint4*)(base + (size_t)(0 * 16 + wv) * 512);
        uint4 ub = *(const uint4*)(base + (size_t)(1 * 16 + wv) * 512);

        for (int kp = 0; kp < 9; ++kp) {
            const int ia = (2 * kp) * 16 + wv;
            const int ib = (2 * kp + 1) * 16 + wv;
            uint4 una, unb;
            if (kp < 8) {   // issue next pair before the compute chain
                una = *(const uint4*)(base + (size_t)((2 * kp + 2) * 16 + wv) * 512);
                unb = *(const uint4*)(base + (size_t)((2 * kp + 3) * 16 + wv) * 512);
            }
            float va[8], vvb[8];
            va[0] = bflo(ua.x); va[1] = bfhi(ua.x);
            va[2] = bflo(ua.y); va[3] = bfhi(ua.y);
            va[4] = bflo(ua.z); va[5] = bfhi(ua.z);
            va[6] = bflo(ua.w); va[7] = bfhi(ua.w);
            vvb[0] = bflo(ub.x); vvb[1] = bfhi(ub.x);
            vvb[2] = bflo(ub.y); vvb[3] = bfhi(ub.y);
            vvb[4] = bflo(ub.z); vvb[5] = bfhi(ub.z);
            vvb[6] = bflo(ub.w); vvb[7] = bfhi(ub.w);

            float rra, rrb;
            if (t == 0) {
                rra = fct_s[ia] * 0.03125f;
                rrb = fct_s[ib] * 0.03125f;
            } else {
                float pa = 0.f, pb2 = 0.f;
                #pragma unroll
                for (int j = 0; j < 8; ++j) {
                    float da = va[j] - mu8[j];
                    float db = vvb[j] - mu8[j];
                    pa  += da * da * is8[j];
                    pb2 += db * db * is8[j];
                }
                pa  = xhalf_sum(pa);      // combine q-halves (xor32, VALU)
                pb2 = xhalf_sum(pb2);
                float acca = kcv - pa;
                float accb = kcv - pb2;
                float mxa = red_max32(acca);
                float mxb = red_max32(accb);
                float ea = __expf(acca - mxa);
                float eb = __expf(accb - mxb);
                float sa = red_sum32(ea);
                float sb = red_sum32(eb);
                rra = (ea / sa) * fct_s[ia];
                rrb = (eb / sb) * fct_s[ib];
            }

            s0 += rra + rrb;
            #pragma unroll
            for (int j = 0; j < 8; ++j) {
                s1[j] += rra * va[j] + rrb * vvb[j];
                s2[j] += rra * va[j] * va[j] + rrb * vvb[j] * vvb[j];
            }
            ua = una; ub = unb;
        }

        // per-wave partials -> LDS (stride 17: 2-way bank alias = free)
        {
            float* dst = &red_s[(wv * 64 + lane) * 17];
            dst[0] = s0;
            #pragma unroll
            for (int j = 0; j < 8; ++j) { dst[1 + j] = s1[j]; dst[9 + j] = s2[j]; }
        }
        __syncthreads();

        // final 16-way reduce + mu/sigma + fused a_out (thread = (c2,q2))
        if (tid < 512) {
            const int c2 = tid >> 4, q2 = tid & 15;
            const int qh2 = q2 >> 3, j2 = q2 & 7;
            float S0 = 0.f, S1 = 0.f, S2 = 0.f;
            #pragma unroll
            for (int wvi = 0; wvi < 16; ++wvi) {
                S0 += red_s[(wvi * 64 + c2) * 17];
                const float* sp = &red_s[(wvi * 64 + qh2 * 32 + c2) * 17];
                S1 += sp[1 + j2];
                S2 += sp[9 + j2];
            }
            float invr = 1.0f / (S0 + EPSV);
            float w0  = S0 * invr;
            float m   = S1 * invr;
            float s2p = S2 * invr;
            float sig = s2p - m * m * (2.0f - w0);   // == sum coeff*(v-mu)^2
            sig = fmaxf(sig + EPSV, 1e-4f);
            float hl = 0.5f * logf(sig);
            mu_s[c2 * 17 + q2]   = m;
            i2ss_s[c2 * 17 + q2] = 1.0f / (2.0f * sig);
            // fused old phase-3: 16-lane DPP row (one c2 per row) sums hl
            float shl = red_sum16(hl);
            if (q2 == 0) {
                float bu  = beta_u[c2];
                float cs  = (16.0f * bu + shl) * S0;
                float arg = LAMBDAV * (beta_a[c2] - cs);
                float ao  = 1.0f / (1.0f + expf(-arg));
                ao = fminf(fmaxf(ao, 1e-4f), 1.0f - 1e-4f);
                aout_s[c2] = ao;
                kc_s[c2]   = logf(ao + EPSV) - shl - 8.0f * LN_2PI;
            }
        }
        __syncthreads();
    }

    // epilogue (fp32): p_out [0,65536) | a_out [65536,69632) | out [69632,139264)
    if (tid < 512) {
        int c2 = tid >> 4, q2 = tid & 15;
        float mu = mu_s[c2 * 17 + q2];
        if (isnan(mu)) mu = 0.f;
        mu = fminf(fmaxf(mu, -10000.f), 10000.f);
        out[(size_t)n * 512 + tid] = mu;
        out[69632 + (size_t)n * 544 + tid] = mu;
        if (tid < 32) {
            float ao = aout_s[tid];
            if (isnan(ao)) ao = 0.5f;
            out[65536 + n * 32 + tid] = ao;
            out[69632 + n * 544 + 512 + tid] = ao;
        }
    }
}

extern "C" void kernel_launch(void* const* d_in, const int* in_sizes, int n_in,
                              void* d_out, int out_size, void* d_ws, size_t ws_size,
                              hipStream_t stream) {
    const float* x  = (const float*)d_in[0];
    const float* w  = (const float*)d_in[1];
    const float* bu = (const float*)d_in[2];
    const float* ba = (const float*)d_in[3];
    float* out = (float*)d_out;
    __hip_bfloat16* v = (__hip_bfloat16*)d_ws;  // 128*288*512 bf16 = 37.7 MB

    conv_v_kernel<<<dim3(576), dim3(256), 0, stream>>>(x, w, v);
    em_routing_kernel<<<dim3(128), dim3(1024), 0, stream>>>(
        x, (const unsigned short*)v, bu, ba, out);
}